// Round 7
// baseline (495.793 us; speedup 1.0000x reference)
//
#include <hip/hip_runtime.h>
#include <hip/hip_cooperative_groups.h>

namespace cg = cooperative_groups;

#define CLS   160          // CLASS_NUM * NUM_PRED
#define TOPKN 1000
#define N0 147456
#define N1 36864
#define N2 9216
#define N3 2304
#define N4 576
#define NROWS (N0 + N1 + N2 + N3)   // 195840 anchors needing top-k keys
#define BD1 N0
#define BD2 (N0 + N1)
#define BD3 (N0 + N1 + N2)
#define NSEL (4 * TOPKN + N4)       // 4576 selected anchors
#define NBINS 65536
#define CAND_CAP 2048
#define GRID 1024
#define NTHREADS (GRID * 256)

struct KParams {
    const float *a0, *a1, *a2, *a3, *a4;
    const float *c0, *c1, *c2, *c3, *c4;
    const float *r0, *r1, *r2, *r3, *r4;
    unsigned *keys, *hist, *coarse, *ctrl;   // ctrl[0..3]=unused thr, [4..7]=cand counts
    uint2 *cand;
    unsigned *sel;
    float *out;
};

__device__ __forceinline__ unsigned sortable(float f) {
    unsigned u = __float_as_uint(f);
    return (u & 0x80000000u) ? ~u : (u | 0x80000000u);
}

__device__ __forceinline__ void level_of(int w, int& level, int& base, int& n) {
    if (w < BD1)      { level = 0; base = 0;   n = N0; }
    else if (w < BD2) { level = 1; base = BD1; n = N1; }
    else if (w < BD3) { level = 2; base = BD2; n = N2; }
    else              { level = 3; base = BD3; n = N3; }
}

// ---------------------------------------------------------------------------
// Single cooperative kernel: 5 phases separated by grid syncs. Replaces the
// 4-kernel pipeline whose ~35us of inter-kernel launch gaps dominated R6.
// ---------------------------------------------------------------------------
__global__ __launch_bounds__(256, 4) void k_mega(KParams p)
{
    __shared__ union {
        unsigned cnt[4096];                                    // P2 (16 KB)
        struct { unsigned s[256], chunk, cum0, thr; } s3a;     // P3a
        unsigned long long a[CAND_CAP];                        // P3b (16 KB)
        struct { float sc[CLS]; float bb[8]; } epi;            // P4
    } u;

    cg::grid_group grid = cg::this_grid();
    int t = threadIdx.x;

    // ======== P1: zero hist|coarse|ctrl + ruler keys ========
    {
        int tid = blockIdx.x * 256 + t;
        for (int i = tid; i < 4 * NBINS + 4096 + 8; i += NTHREADS)
            p.hist[i] = 0;    // hist, coarse, ctrl are contiguous

        int wv   = t >> 6;
        int lane = t & 63;
        int sub  = lane >> 3;   // row within group of 8
        int col  = lane & 7;    // float4 column group
        for (int tile = blockIdx.x; tile < NROWS / 128; tile += GRID) {
            int r0 = tile << 7;
            const float* cb; int lvl, base, n;
            level_of(r0, lvl, base, n);
            cb = (lvl == 0) ? p.c0 : (lvl == 1) ? p.c1 : (lvl == 2) ? p.c2 : p.c3;
            int lr0 = r0 - base;
            #pragma unroll
            for (int i = 0; i < 4; ++i) {
                int rrel = wv * 32 + i * 8 + sub;
                const float4* q = (const float4*)cb + (size_t)(lr0 + rrel) * 40 + col;
                float m = -3.4e38f;
                #pragma unroll
                for (int k = 0; k < 5; ++k) {
                    float4 v = q[8 * k];
                    m = fmaxf(m, fmaxf(fmaxf(v.x, v.y), fmaxf(v.z, v.w)));
                }
                m = fmaxf(m, __shfl_xor(m, 1));
                m = fmaxf(m, __shfl_xor(m, 2));
                m = fmaxf(m, __shfl_xor(m, 4));
                if (col == 0) p.keys[r0 + rrel] = sortable(m);
            }
        }
    }
    grid.sync();

    // ======== P2: chunked segment histogram (1024 block-units) ========
    {
        int b        = blockIdx.x;
        int level    = b >> 8;
        unsigned seg = (b >> 4) & 15;
        int chunk    = b & 15;
        for (int i = t; i < 4096; i += 256) u.cnt[i] = 0;
        __syncthreads();
        int base = (level == 0) ? 0 : (level == 1) ? BD1 : (level == 2) ? BD2 : BD3;
        int n    = (level == 0) ? N0 : (level == 1) ? N1 : (level == 2) ? N2 : N3;
        int q = n >> 4;
        const uint4* kp = (const uint4*)(p.keys + base + chunk * q);
        int nv = q >> 2;
        for (int i = t; i < nv; i += 256) {
            uint4 k = kp[i];
            unsigned b0 = k.x >> 16, b1 = k.y >> 16, b2 = k.z >> 16, b3 = k.w >> 16;
            if ((b0 >> 12) == seg) atomicAdd(&u.cnt[b0 & 4095u], 1u);
            if ((b1 >> 12) == seg) atomicAdd(&u.cnt[b1 & 4095u], 1u);
            if ((b2 >> 12) == seg) atomicAdd(&u.cnt[b2 & 4095u], 1u);
            if ((b3 >> 12) == seg) atomicAdd(&u.cnt[b3 & 4095u], 1u);
        }
        __syncthreads();
        unsigned* h = p.hist + level * NBINS + (seg << 12);
        for (int i = t; i < 4096; i += 256) {
            unsigned c = u.cnt[i];
            if (c) atomicAdd(&h[i], c);
        }
        if (t < 64) {
            int j = t;
            unsigned s2 = 0;
            #pragma unroll 8
            for (int i = 0; i < 64; ++i) s2 += u.cnt[j * 64 + ((i + j) & 63)];
            if (s2) atomicAdd(&p.coarse[level * 1024 + (int)(seg << 6) + j], s2);
        }
    }
    grid.sync();

    // ======== P3a: threshold (redundant per block) + sliced compaction ========
    if (blockIdx.x < 64) {
        int level = blockIdx.x >> 4;
        int slice = blockIdx.x & 15;
        const unsigned* co = p.coarse + level * 1024;
        unsigned c0v = co[4 * t], c1v = co[4 * t + 1],
                 c2v = co[4 * t + 2], c3v = co[4 * t + 3];
        unsigned l3 = c3v, l2 = c2v + l3, l1 = c1v + l2, l0 = c0v + l1;
        u.s3a.s[t] = l0;
        __syncthreads();
        for (int off = 1; off < 256; off <<= 1) {     // suffix sums over totals
            unsigned v   = u.s3a.s[t];
            unsigned add = (t + off < 256) ? u.s3a.s[t + off] : 0u;
            __syncthreads();
            u.s3a.s[t] = v + add;
            __syncthreads();
        }
        unsigned after = (t < 255) ? u.s3a.s[t + 1] : 0u;
        unsigned suf[4] = {l0 + after, l1 + after, l2 + after, l3 + after};
        unsigned nxt[4] = {l1 + after, l2 + after, l3 + after, after};
        #pragma unroll
        for (int j = 0; j < 4; ++j)
            if (suf[j] >= TOPKN && nxt[j] < TOPKN) {
                u.s3a.chunk = (unsigned)(4 * t + j);
                u.s3a.cum0  = nxt[j];
            }
        __syncthreads();
        if (t < 64) {    // fine refine within the 64-bin edge chunk (wave 0)
            const unsigned* h = p.hist + level * NBINS;
            unsigned c = h[u.s3a.chunk * 64 + (unsigned)t];
            unsigned sufw = c;
            #pragma unroll
            for (int off = 1; off < 64; off <<= 1) {
                unsigned v = __shfl_down(sufw, off);
                if (t + off < 64) sufw += v;
            }
            unsigned long long mask = __ballot(u.s3a.cum0 + sufw >= TOPKN);
            if (t == 0)
                u.s3a.thr = (u.s3a.chunk * 64 + (63 - (unsigned)__clzll(mask))) << 16;
        }
        __syncthreads();
        unsigned thr = u.s3a.thr;

        int base = (level == 0) ? 0 : (level == 1) ? BD1 : (level == 2) ? BD2 : BD3;
        int n    = (level == 0) ? N0 : (level == 1) ? N1 : (level == 2) ? N2 : N3;
        int ns = n >> 4;                         // slice length
        const uint4* kp = (const uint4*)(p.keys + base + slice * ns);
        int nv = ns >> 2;
        int lane = t & 63;
        for (int i = t; i < nv; i += 256) {
            uint4 k4 = kp[i];
            unsigned kv[4] = {k4.x, k4.y, k4.z, k4.w};
            #pragma unroll
            for (int c = 0; c < 4; ++c) {
                bool pass = kv[c] >= thr;
                unsigned long long mask = __ballot(pass);
                if (pass) {
                    int leader    = __ffsll((long long)mask) - 1;
                    unsigned tot  = (unsigned)__popcll(mask);
                    unsigned rank = (unsigned)__popcll(mask & ((1ull << lane) - 1ull));
                    unsigned bp = 0;
                    if (lane == leader) bp = atomicAdd(&p.ctrl[4 + level], tot);
                    bp = (unsigned)__shfl((int)bp, leader);
                    unsigned pos = bp + rank;
                    if (pos < CAND_CAP)
                        p.cand[level * CAND_CAP + pos] =
                            make_uint2(kv[c], (unsigned)(slice * ns + 4 * i + c));
                }
            }
        }
    }
    grid.sync();

    // ======== P3b: exact stable rank (16 blocks/level, 4096 thr >= cnt) ========
    if (blockIdx.x < 64) {
        int level = blockIdx.x >> 4;
        int slice = blockIdx.x & 15;
        unsigned cnt = p.ctrl[4 + level];
        if (cnt > CAND_CAP) cnt = CAND_CAP;
        for (int i = t; i < (int)cnt; i += 256) {
            uint2 c = p.cand[level * CAND_CAP + i];
            u.a[i] = ((unsigned long long)c.x << 32) | (unsigned)(~c.y);
        }
        __syncthreads();
        int e = slice * 256 + t;
        if (e < (int)cnt) {
            unsigned long long mine = u.a[e];
            unsigned rank = 0;
            for (int j = 0; j < (int)cnt; ++j) rank += (u.a[j] > mine) ? 1u : 0u;
            if (rank < TOPKN)
                p.sel[level * TOPKN + rank] = ~(unsigned)(mine & 0xFFFFFFFFull);
        }
    }
    grid.sync();

    // ======== P4: epilogue, grid-stride over 4576 selected anchors ========
    for (int s = blockIdx.x; s < NSEL; s += GRID) {
        int level, idx;
        if (s < 4 * TOPKN) {
            level = s / TOPKN;
            idx   = (int)p.sel[s];
        } else {
            level = 4;
            idx   = s - 4 * TOPKN;
        }
        const float *A, *C, *R;
        switch (level) {
            case 0: A = p.a0; C = p.c0; R = p.r0; break;
            case 1: A = p.a1; C = p.c1; R = p.r1; break;
            case 2: A = p.a2; C = p.c2; R = p.r2; break;
            case 3: A = p.a3; C = p.c3; R = p.r3; break;
            default: A = p.a4; C = p.c4; R = p.r4; break;
        }
        const float* cp = C + (size_t)idx * CLS;
        if (t < CLS) {
            float x = cp[t];
            u.epi.sc[t] = 1.0f / (1.0f + __expf(-x));
        }
        if (t == 192) {
            const float* ap = A + (size_t)idx * 4;
            const float* rp = R + (size_t)idx * 8;
            float x1 = ap[0], y1 = ap[1], x2 = ap[2], y2 = ap[3];
            float w  = x2 - x1 + 1.0f, h = y2 - y1 + 1.0f;
            float cx = x1 + 0.5f * w,  cy = y1 + 0.5f * h;
            #pragma unroll
            for (int q2 = 0; q2 < 2; ++q2) {
                float pcx = cx + rp[4 * q2 + 0] * w;
                float pcy = cy + rp[4 * q2 + 1] * h;
                float pw  = w * __expf(rp[4 * q2 + 2]);
                float ph  = h * __expf(rp[4 * q2 + 3]);
                u.epi.bb[4 * q2 + 0] = pcx - 0.5f * pw;
                u.epi.bb[4 * q2 + 1] = pcy - 0.5f * ph;
                u.epi.bb[4 * q2 + 2] = pcx + 0.5f * pw;
                u.epi.bb[4 * q2 + 3] = pcy + 0.5f * ph;
            }
        }
        __syncthreads();
        float4* orow = (float4*)(p.out + (size_t)s * 960);
        if (t < 240) {
            int j = t / 3, part = t % 3;
            float tag = (float)(j + 1);
            float4 v;
            if (part == 0)      v = make_float4(u.epi.bb[0], u.epi.bb[1], u.epi.bb[2], u.epi.bb[3]);
            else if (part == 1) v = make_float4(u.epi.sc[j], tag, u.epi.bb[4], u.epi.bb[5]);
            else                v = make_float4(u.epi.bb[6], u.epi.bb[7], u.epi.sc[80 + j], tag);
            orow[t] = v;
        }
        __syncthreads();   // u.epi reused next iteration
    }
}

// ---------------------------------------------------------------------------
// Workspace (uint32 words):
//   keys[NROWS] | hist[4*NBINS] | coarse[4096] | ctrl[8] | cand[4*CAND_CAP]
//   (uint2) | sel[4*TOPKN]   (~1.9 MB). hist..ctrl zeroed in P1 each call.
// ---------------------------------------------------------------------------
extern "C" void kernel_launch(void* const* d_in, const int* in_sizes, int n_in,
                              void* d_out, int out_size, void* d_ws, size_t ws_size,
                              hipStream_t stream)
{
    bool interleaved = (in_sizes[1] > 1000000);
    const float *A[5], *C[5], *R[5];
    for (int i = 0; i < 5; ++i) {
        if (interleaved) {
            A[i] = (const float*)d_in[3 * i + 0];
            C[i] = (const float*)d_in[3 * i + 1];
            R[i] = (const float*)d_in[3 * i + 2];
        } else {
            A[i] = (const float*)d_in[i];
            C[i] = (const float*)d_in[5 + i];
            R[i] = (const float*)d_in[10 + i];
        }
    }

    unsigned* keys   = (unsigned*)d_ws;
    unsigned* hist   = keys + NROWS;
    unsigned* coarse = hist + 4 * NBINS;
    unsigned* ctrl   = coarse + 4096;
    uint2*    cand   = (uint2*)(ctrl + 8);
    unsigned* sel    = (unsigned*)(cand + 4 * CAND_CAP);

    KParams p;
    p.a0 = A[0]; p.a1 = A[1]; p.a2 = A[2]; p.a3 = A[3]; p.a4 = A[4];
    p.c0 = C[0]; p.c1 = C[1]; p.c2 = C[2]; p.c3 = C[3]; p.c4 = C[4];
    p.r0 = R[0]; p.r1 = R[1]; p.r2 = R[2]; p.r3 = R[3]; p.r4 = R[4];
    p.keys = keys; p.hist = hist; p.coarse = coarse; p.ctrl = ctrl;
    p.cand = cand; p.sel = sel; p.out = (float*)d_out;

    void* args[] = { &p };
    hipLaunchCooperativeKernel((const void*)k_mega, dim3(GRID), dim3(256),
                               args, 0, stream);
}

// Round 8
// 90.082 us; speedup vs baseline: 5.5038x; 5.5038x over previous
//
#include <hip/hip_runtime.h>

#define CLS   160          // CLASS_NUM * NUM_PRED
#define TOPKN 1000
#define N0 147456
#define N1 36864
#define N2 9216
#define N3 2304
#define N4 576
#define NROWS (N0 + N1 + N2 + N3)   // 195840 anchors needing top-k keys
#define BD1 N0
#define BD2 (N0 + N1)
#define BD3 (N0 + N1 + N2)
#define NSEL (4 * TOPKN + N4)       // 4576 selected anchors
#define NBINS 65536
#define CAND_CAP 2048

__device__ __forceinline__ unsigned sortable(float f) {
    unsigned u = __float_as_uint(f);
    return (u & 0x80000000u) ? ~u : (u | 0x80000000u);
}

// ---------------------------------------------------------------------------
// K1: ruler keys, NO atomics. Block b owns rows [b*128, b*128+128) — always
// within one level. 8 lanes per row, 5 float4 loads per lane, 3-step shuffle
// reduce. Also zeroes hist|coarse|ctrl (contiguous, 266248 words <= 391680
// threads) so no memset kernel is needed.
// ---------------------------------------------------------------------------
__global__ __launch_bounds__(256) void k_ruler(
    const float* __restrict__ c0, const float* __restrict__ c1,
    const float* __restrict__ c2, const float* __restrict__ c3,
    unsigned* __restrict__ keys, unsigned* __restrict__ hist)
{
    int tid = blockIdx.x * 256 + threadIdx.x;
    if (tid < 4 * NBINS + 4096 + 8) hist[tid] = 0;

    int r0 = blockIdx.x << 7;             // first global row of this block
    const float* cb; int lr0;
    if (r0 < BD1)      { cb = c0; lr0 = r0; }
    else if (r0 < BD2) { cb = c1; lr0 = r0 - BD1; }
    else if (r0 < BD3) { cb = c2; lr0 = r0 - BD2; }
    else               { cb = c3; lr0 = r0 - BD3; }

    int wv   = threadIdx.x >> 6;
    int lane = threadIdx.x & 63;
    int sub  = lane >> 3;   // row within group of 8
    int col  = lane & 7;    // float4 column group
    #pragma unroll
    for (int i = 0; i < 4; ++i) {
        int rrel = wv * 32 + i * 8 + sub;
        const float4* p = (const float4*)cb + (size_t)(lr0 + rrel) * 40 + col;
        float m = -3.4e38f;
        #pragma unroll
        for (int k = 0; k < 5; ++k) {
            float4 v = p[8 * k];
            m = fmaxf(m, fmaxf(fmaxf(v.x, v.y), fmaxf(v.z, v.w)));
        }
        m = fmaxf(m, __shfl_xor(m, 1));
        m = fmaxf(m, __shfl_xor(m, 2));
        m = fmaxf(m, __shfl_xor(m, 4));
        if (col == 0) keys[r0 + rrel] = sortable(m);
    }
}

// ---------------------------------------------------------------------------
// K2: chunked segment histogram. 1024 blocks = (level, 16 segments, 16
// chunks). LDS-counts its segment's bins, flushes nonzero bins into the
// pre-zeroed hist, plus per-64-bin-chunk sums into coarse[level][1024].
// ---------------------------------------------------------------------------
__global__ __launch_bounds__(256) void k_hist(const unsigned* __restrict__ keys,
                                              unsigned* __restrict__ hist,
                                              unsigned* __restrict__ coarse)
{
    int b        = blockIdx.x;       // 1024 blocks
    int level    = b >> 8;
    unsigned seg = (b >> 4) & 15;
    int chunk    = b & 15;
    __shared__ unsigned cnt[4096];
    for (int i = threadIdx.x; i < 4096; i += 256) cnt[i] = 0;
    __syncthreads();
    int base, n;
    switch (level) {
        case 0:  base = 0;   n = N0; break;
        case 1:  base = BD1; n = N1; break;
        case 2:  base = BD2; n = N2; break;
        default: base = BD3; n = N3; break;
    }
    int q = n >> 4;                         // chunk size
    const uint4* kp = (const uint4*)(keys + base + chunk * q);
    int nv = q >> 2;
    for (int i = threadIdx.x; i < nv; i += 256) {
        uint4 k = kp[i];
        unsigned b0 = k.x >> 16, b1 = k.y >> 16, b2 = k.z >> 16, b3 = k.w >> 16;
        if ((b0 >> 12) == seg) atomicAdd(&cnt[b0 & 4095u], 1u);
        if ((b1 >> 12) == seg) atomicAdd(&cnt[b1 & 4095u], 1u);
        if ((b2 >> 12) == seg) atomicAdd(&cnt[b2 & 4095u], 1u);
        if ((b3 >> 12) == seg) atomicAdd(&cnt[b3 & 4095u], 1u);
    }
    __syncthreads();
    unsigned* h = hist + level * NBINS + (seg << 12);
    for (int i = threadIdx.x; i < 4096; i += 256) {
        unsigned c = cnt[i];
        if (c) atomicAdd(&h[i], c);
    }
    if (threadIdx.x < 64) {
        int j = threadIdx.x;
        unsigned s2 = 0;
        #pragma unroll 8
        for (int i = 0; i < 64; ++i) s2 += cnt[j * 64 + ((i + j) & 63)];
        if (s2) atomicAdd(&coarse[level * 1024 + (int)(seg << 6) + j], s2);
    }
}

// ---------------------------------------------------------------------------
// K3: sliced compaction, 64 blocks x 1024 = (level, 16 slices). Each block
// REDUNDANTLY computes the threshold from coarse+hist (cheap, ~1us; kernel
// boundary guarantees coherence of the atomically-built hist), then scans
// only its 1/16 key slice — fixes R5/R6's hidden ~50us single-CU scan of
// remote-dirty keys. Wave-aggregated global append into cand.
// ---------------------------------------------------------------------------
__global__ __launch_bounds__(1024) void k_compact(const unsigned* __restrict__ keys,
                                                  const unsigned* __restrict__ hist,
                                                  const unsigned* __restrict__ coarse,
                                                  unsigned* __restrict__ ctrl,
                                                  uint2* __restrict__ cand)
{
    int level = blockIdx.x >> 4;
    int slice = blockIdx.x & 15;
    int t     = threadIdx.x;
    int lane  = t & 63;

    __shared__ unsigned s[1024];
    __shared__ unsigned thr_s, chunk_s, cum0_s;

    // ---- decide threshold (same math as R6, verified) ----
    s[t] = coarse[level * 1024 + t];
    __syncthreads();
    for (int off = 1; off < 1024; off <<= 1) {   // suffix sums
        unsigned v   = s[t];
        unsigned add = (t + off < 1024) ? s[t + off] : 0u;
        __syncthreads();
        s[t] = v + add;
        __syncthreads();
    }
    if (s[t] >= TOPKN && (t == 1023 || s[t + 1] < TOPKN)) {
        chunk_s = (unsigned)t;
        cum0_s  = (t == 1023) ? 0u : s[t + 1];
    }
    __syncthreads();
    if (t < 64) {    // fine refine within the 64-bin edge chunk (wave 0)
        const unsigned* h = hist + level * NBINS;
        unsigned c = h[chunk_s * 64 + (unsigned)t];
        unsigned sufw = c;
        #pragma unroll
        for (int off = 1; off < 64; off <<= 1) {
            unsigned v = __shfl_down(sufw, off);
            if (t + off < 64) sufw += v;
        }
        unsigned long long mask = __ballot(cum0_s + sufw >= TOPKN);
        if (t == 0)
            thr_s = (chunk_s * 64 + (63 - (unsigned)__clzll(mask))) << 16;
    }
    __syncthreads();
    unsigned thr = thr_s;

    // ---- sliced compaction ----
    int base = (level == 0) ? 0 : (level == 1) ? BD1 : (level == 2) ? BD2 : BD3;
    int n    = (level == 0) ? N0 : (level == 1) ? N1 : (level == 2) ? N2 : N3;
    int ns = n >> 4;                         // slice length (keys)
    const uint4* kp = (const uint4*)(keys + base + slice * ns);
    int nv = ns >> 2;
    for (int i = t; i < nv; i += 1024) {
        uint4 k4 = kp[i];
        unsigned kv[4] = {k4.x, k4.y, k4.z, k4.w};
        #pragma unroll
        for (int c = 0; c < 4; ++c) {
            bool pass = kv[c] >= thr;
            unsigned long long mask = __ballot(pass);
            if (pass) {
                int leader    = __ffsll((long long)mask) - 1;
                unsigned tot  = (unsigned)__popcll(mask);
                unsigned rank = (unsigned)__popcll(mask & ((1ull << lane) - 1ull));
                unsigned bp = 0;
                if (lane == leader) bp = atomicAdd(&ctrl[4 + level], tot);
                bp = (unsigned)__shfl((int)bp, leader);
                unsigned pos = bp + rank;
                if (pos < CAND_CAP)
                    cand[level * CAND_CAP + pos] =
                        make_uint2(kv[c], (unsigned)(slice * ns + 4 * i + c));
            }
        }
    }
}

// ---------------------------------------------------------------------------
// K4: exact stable top-k order. Composite = (key << 32) | ~idx, brute-force
// rank over ~1100 candidates — descending key, ties ascending index (exact
// lax.top_k semantics). 4 blocks x 1024.
// ---------------------------------------------------------------------------
__global__ __launch_bounds__(1024) void k_rank(const uint2* __restrict__ cand,
                                               const unsigned* __restrict__ ctrl,
                                               unsigned* __restrict__ sel)
{
    int level = blockIdx.x;
    unsigned cnt = ctrl[4 + level];
    if (cnt > CAND_CAP) cnt = CAND_CAP;
    __shared__ unsigned long long a[CAND_CAP];
    for (int i = threadIdx.x; i < (int)cnt; i += 1024) {
        uint2 c = cand[level * CAND_CAP + i];
        a[i] = ((unsigned long long)c.x << 32) | (unsigned)(~c.y);
    }
    __syncthreads();
    for (int i = threadIdx.x; i < (int)cnt; i += 1024) {
        unsigned long long mine = a[i];
        unsigned rank = 0;
        for (int j = 0; j < (int)cnt; ++j) rank += (a[j] > mine) ? 1u : 0u;
        if (rank < TOPKN)
            sel[level * TOPKN + rank] = ~(unsigned)(mine & 0xFFFFFFFFull);
    }
}

// ---------------------------------------------------------------------------
// K5: one block per selected anchor. Gather cls row -> sigmoid in LDS, decode
// both bboxes, emit 80 rows x 12 floats as 240 coalesced float4 stores.
// Row layout: [b0(4), score0, tag, b1(4), score1, tag]
// ---------------------------------------------------------------------------
__global__ __launch_bounds__(256) void k_epilogue(
    const float* a0, const float* a1, const float* a2, const float* a3, const float* a4,
    const float* c0, const float* c1, const float* c2, const float* c3, const float* c4,
    const float* r0, const float* r1, const float* r2, const float* r3, const float* r4,
    const unsigned* __restrict__ sel, float* __restrict__ out)
{
    int s = blockIdx.x;
    int level, idx;
    if (s < 4 * TOPKN) {
        level = s / TOPKN;
        idx   = (int)sel[s];          // sel laid out level*1000 + rank == s
    } else {
        level = 4;
        idx   = s - 4 * TOPKN;
    }
    const float *A, *C, *R;
    switch (level) {
        case 0: A = a0; C = c0; R = r0; break;
        case 1: A = a1; C = c1; R = r1; break;
        case 2: A = a2; C = c2; R = r2; break;
        case 3: A = a3; C = c3; R = r3; break;
        default: A = a4; C = c4; R = r4; break;
    }

    __shared__ float sc[CLS];
    __shared__ float bb[8];

    const float* cp = C + (size_t)idx * CLS;
    if (threadIdx.x < CLS) {
        float x = cp[threadIdx.x];
        sc[threadIdx.x] = 1.0f / (1.0f + __expf(-x));
    }
    if (threadIdx.x == 192) {   // wave 3, not used by the cls gather
        const float* ap = A + (size_t)idx * 4;
        const float* rp = R + (size_t)idx * 8;
        float x1 = ap[0], y1 = ap[1], x2 = ap[2], y2 = ap[3];
        float w  = x2 - x1 + 1.0f, h = y2 - y1 + 1.0f;
        float cx = x1 + 0.5f * w,  cy = y1 + 0.5f * h;
        #pragma unroll
        for (int p = 0; p < 2; ++p) {
            float pcx = cx + rp[4 * p + 0] * w;
            float pcy = cy + rp[4 * p + 1] * h;
            float pw  = w * __expf(rp[4 * p + 2]);
            float ph  = h * __expf(rp[4 * p + 3]);
            bb[4 * p + 0] = pcx - 0.5f * pw;
            bb[4 * p + 1] = pcy - 0.5f * ph;
            bb[4 * p + 2] = pcx + 0.5f * pw;
            bb[4 * p + 3] = pcy + 0.5f * ph;
        }
    }
    __syncthreads();

    float4* orow = (float4*)(out + (size_t)s * 960);   // 80 * 12 floats
    if (threadIdx.x < 240) {
        int j = threadIdx.x / 3, part = threadIdx.x % 3;
        float tag = (float)(j + 1);
        float4 v;
        if (part == 0)      v = make_float4(bb[0], bb[1], bb[2], bb[3]);
        else if (part == 1) v = make_float4(sc[j], tag, bb[4], bb[5]);
        else                v = make_float4(bb[6], bb[7], sc[80 + j], tag);
        orow[threadIdx.x] = v;
    }
}

// ---------------------------------------------------------------------------
// Workspace (uint32 words):
//   keys[NROWS] | hist[4*NBINS] | coarse[4096] | ctrl[8] | cand[4*CAND_CAP]
//   (uint2) | sel[4*TOPKN]   (~1.9 MB). hist|coarse|ctrl zeroed by k_ruler.
// ---------------------------------------------------------------------------
extern "C" void kernel_launch(void* const* d_in, const int* in_sizes, int n_in,
                              void* d_out, int out_size, void* d_ws, size_t ws_size,
                              hipStream_t stream)
{
    bool interleaved = (in_sizes[1] > 1000000);
    const float *A[5], *C[5], *R[5];
    for (int i = 0; i < 5; ++i) {
        if (interleaved) {
            A[i] = (const float*)d_in[3 * i + 0];
            C[i] = (const float*)d_in[3 * i + 1];
            R[i] = (const float*)d_in[3 * i + 2];
        } else {
            A[i] = (const float*)d_in[i];
            C[i] = (const float*)d_in[5 + i];
            R[i] = (const float*)d_in[10 + i];
        }
    }

    unsigned* keys   = (unsigned*)d_ws;
    unsigned* hist   = keys + NROWS;
    unsigned* coarse = hist + 4 * NBINS;
    unsigned* ctrl   = coarse + 4096;
    uint2*    cand   = (uint2*)(ctrl + 8);
    unsigned* sel    = (unsigned*)(cand + 4 * CAND_CAP);

    k_ruler<<<1530, 256, 0, stream>>>(C[0], C[1], C[2], C[3], keys, hist);
    k_hist<<<1024, 256, 0, stream>>>(keys, hist, coarse);
    k_compact<<<64, 1024, 0, stream>>>(keys, hist, coarse, ctrl, cand);
    k_rank<<<4, 1024, 0, stream>>>(cand, ctrl, sel);
    k_epilogue<<<NSEL, 256, 0, stream>>>(A[0], A[1], A[2], A[3], A[4],
                                         C[0], C[1], C[2], C[3], C[4],
                                         R[0], R[1], R[2], R[3], R[4],
                                         sel, (float*)d_out);
}